// Round 17
// baseline (1538.870 us; speedup 1.0000x reference)
//
#include <hip/hip_runtime.h>
#include <cstdint>
#include <cstddef>

#define Tn 2048
#define Bn 2
#define Hn 12
#define Cn 768
#define Ln 4
#define Vn 50257

typedef unsigned short ushort_t;
typedef __attribute__((ext_vector_type(8))) __bf16 bf16x8;
typedef __attribute__((ext_vector_type(8))) unsigned short u16x8;
typedef __attribute__((ext_vector_type(4))) unsigned short u16x4;
typedef __attribute__((ext_vector_type(4))) float f32x4;

static constexpr size_t QKV_ELEMS = (size_t)Bn * Hn * Tn * 64;  // 3,145,728
static constexpr size_t OFF_QKV = 0;
static constexpr size_t OFF_APROJ = 1769472;
static constexpr size_t OFF_FC = 2359296;
static constexpr size_t OFF_MPROJ = 4718592;
static constexpr size_t PACK_SZ = 7077888;

__device__ inline unsigned short f2bf(float f) {
  unsigned int u = __float_as_uint(f);
  unsigned int r = (u + 0x7fffu + ((u >> 16) & 1u)) >> 16;
  return (unsigned short)r;
}

__device__ inline f32x4 zero4() { f32x4 z; z[0]=0.f; z[1]=0.f; z[2]=0.f; z[3]=0.f; return z; }

__device__ inline void gload_lds16(const ushort_t* g, ushort_t* l) {
  __builtin_amdgcn_global_load_lds(
      (const __attribute__((address_space(1))) void*)g,
      (__attribute__((address_space(3))) void*)l, 16, 0, 0);
}

// bijective XCD-chunked swizzle (m204)
__device__ inline int swz_lin() {
  int nbm = gridDim.x;
  int lin = blockIdx.y * nbm + blockIdx.x;
  int nwg = nbm * gridDim.y;
  int q = nwg >> 3, r = nwg & 7, x = lin & 7, p = lin >> 3;
  return (x < r ? x * (q + 1) : r * (q + 1) + (x - r) * q) + p;
}

// ---------------- embedding (float4) ----------------
__global__ __launch_bounds__(192) void embed_kernel(const int* __restrict__ idx,
    const float* __restrict__ tok, const float* __restrict__ pos, float* __restrict__ x) {
  int row = blockIdx.x;
  int t = row & (Tn - 1);
  int token = idx[row];
  const f32x4* tr = (const f32x4*)(tok + (size_t)token * Cn);
  const f32x4* pr = (const f32x4*)(pos + (size_t)t * Cn);
  f32x4* xr = (f32x4*)(x + (size_t)row * Cn);
  xr[threadIdx.x] = tr[threadIdx.x] + pr[threadIdx.x];
}

// ---------------- layernorm -> bf16 (wave per row, float4) ----------------
__global__ __launch_bounds__(256) void ln_kernel(const float* __restrict__ x,
    const float* __restrict__ gam, const float* __restrict__ bet, ushort_t* __restrict__ out) {
  const int wv = threadIdx.x >> 6, lane = threadIdx.x & 63;
  const int row = blockIdx.x * 4 + wv;
  const f32x4* xr = (const f32x4*)(x + (size_t)row * Cn);
  f32x4 v[3]; float s = 0.f, s2 = 0.f;
  #pragma unroll
  for (int e = 0; e < 3; ++e) {
    v[e] = xr[lane + e*64];
    #pragma unroll
    for (int j = 0; j < 4; ++j) { s += v[e][j]; s2 += v[e][j]*v[e][j]; }
  }
  #pragma unroll
  for (int off = 32; off >= 1; off >>= 1) { s += __shfl_xor(s, off); s2 += __shfl_xor(s2, off); }
  float mean = s * (1.f / Cn);
  float var  = s2 * (1.f / Cn) - mean * mean;
  float rstd = rsqrtf(var + 1e-5f);
  const f32x4* g4 = (const f32x4*)gam;
  const f32x4* b4 = (const f32x4*)bet;
  u16x4* o4 = (u16x4*)(out + (size_t)row * Cn);
  #pragma unroll
  for (int e = 0; e < 3; ++e) {
    f32x4 gv = g4[lane + e*64], bv = b4[lane + e*64];
    u16x4 o;
    #pragma unroll
    for (int j = 0; j < 4; ++j) o[j] = f2bf((v[e][j] - mean) * rstd * gv[j] + bv[j]);
    o4[lane + e*64] = o;
  }
}

// ---------------- transpose + f32->bf16 (head weight) ----------------
__global__ __launch_bounds__(256) void tcvt_kernel(const float* __restrict__ in,
    ushort_t* __restrict__ out, int K, int N, int Npad) {
  __shared__ float tile[32][33];
  int n0 = blockIdx.x * 32, k0 = blockIdx.y * 32;
  int tx = threadIdx.x, ty = threadIdx.y;
  #pragma unroll
  for (int r = 0; r < 4; ++r) {
    int k = k0 + ty + 8*r;
    int n = n0 + tx;
    tile[ty + 8*r][tx] = (n < N) ? in[(size_t)k * N + n] : 0.f;
  }
  __syncthreads();
  #pragma unroll
  for (int r = 0; r < 4; ++r) {
    int n = n0 + ty + 8*r;
    out[(size_t)n * K + k0 + tx] = f2bf(tile[tx][ty + 8*r]);
  }
}

// ---------------- ALL layers' weight transpose+convert (one launch) ----------------
__global__ __launch_bounds__(256) void tcvtAll_kernel(const float* __restrict__ qkvw,
    const float* __restrict__ aprojw, const float* __restrict__ fcw,
    const float* __restrict__ mprojw, ushort_t* __restrict__ wT) {
  __shared__ float tile[32][33];
  int bid = blockIdx.x;
  const int layer = bid / 6912;
  int local = bid - layer * 6912;
  const float* in; int K, N, tilesX; size_t ooff;
  if (local < 1728)      { in = qkvw   + (size_t)layer*1769472; K = 768;  N = 2304; tilesX = 72; ooff = OFF_QKV; }
  else if (local < 2304) { in = aprojw + (size_t)layer*589824;  K = 768;  N = 768;  tilesX = 24; ooff = OFF_APROJ; local -= 1728; }
  else if (local < 4608) { in = fcw    + (size_t)layer*2359296; K = 768;  N = 3072; tilesX = 96; ooff = OFF_FC;    local -= 2304; }
  else                   { in = mprojw + (size_t)layer*2359296; K = 3072; N = 768;  tilesX = 24; ooff = OFF_MPROJ; local -= 4608; }
  int n0 = (local % tilesX) * 32, k0 = (local / tilesX) * 32;
  int tx = threadIdx.x, ty = threadIdx.y;
  ushort_t* out = wT + (size_t)layer * PACK_SZ + ooff;
  #pragma unroll
  for (int r = 0; r < 4; ++r)
    tile[ty + 8*r][tx] = in[(size_t)(k0 + ty + 8*r) * N + n0 + tx];
  __syncthreads();
  #pragma unroll
  for (int r = 0; r < 4; ++r)
    out[(size_t)(n0 + ty + 8*r) * K + k0 + tx] = f2bf(tile[tx][ty + 8*r]);
}

// ---------------- bf16 64x64 tile transpose: [BH,T,64] -> [BH,64,T] ----------------
__global__ __launch_bounds__(256) void vtrans_kernel(const ushort_t* __restrict__ vin,
                                                     ushort_t* __restrict__ vout) {
  __shared__ ushort_t tile[64][65];
  int t0 = blockIdx.x * 64;
  size_t bh = blockIdx.y;
  const ushort_t* src = vin + (bh * Tn + t0) * 64;
  int row = threadIdx.x >> 2, c0 = (threadIdx.x & 3) * 16;
  u16x8 a = *(const u16x8*)&src[(size_t)row * 64 + c0];
  u16x8 b = *(const u16x8*)&src[(size_t)row * 64 + c0 + 8];
  #pragma unroll
  for (int j = 0; j < 8; ++j) { tile[row][c0 + j] = a[j]; tile[row][c0 + 8 + j] = b[j]; }
  __syncthreads();
  int d = threadIdx.x >> 2, tq = (threadIdx.x & 3) * 16;
  u16x8 o0, o1;
  #pragma unroll
  for (int j = 0; j < 8; ++j) { o0[j] = tile[tq + j][d]; o1[j] = tile[tq + 8 + j][d]; }
  ushort_t* dst = vout + (bh * 64 + d) * Tn + t0 + tq;
  *(u16x8*)&dst[0] = o0;
  *(u16x8*)&dst[8] = o1;
}

// ======== 256x128 8-wave GEMM: 3-buf ring (72KB -> 2 blocks/CU) + T2 swizzle, G=4 ========
// MODE 0: f32 = acc+bias ; 2: bf16 = gelu(acc+bias) ; 3: qkv scatter
template<int MODE>
__global__ __launch_bounds__(512) void gemm256_kernel(
    const ushort_t* __restrict__ A, const ushort_t* __restrict__ Bt,
    const float* __restrict__ bias, void* __restrict__ outp,
    int M, int N, int K) {
  constexpr int BUFE = 12288;
  __shared__ ushort_t lds[3 * BUFE];
  const int t = threadIdx.x;
  const int w = t >> 6, l = t & 63, lo = l & 15, g = l >> 4;
  const int wm = w >> 1, wn = w & 1;

  int bm, bn;
  {
    int seq = swz_lin();
    int gsz = 4 * gridDim.y;
    int grp = seq / gsz;
    int t2 = seq - grp * gsz;
    bn = t2 >> 2;
    bm = grp * 4 + (t2 & 3);
  }

  const ushort_t* gAb = A  + (size_t)bm * 256 * K;
  const ushort_t* gBb = Bt + (size_t)bn * 128 * K;

  f32x4 acc[4][4];
  #pragma unroll
  for (int i = 0; i < 4; ++i)
    #pragma unroll
    for (int j = 0; j < 4; ++j) acc[i][j] = zero4();

  auto stage = [&](int kt, int buf) {
    const int k0 = kt << 5;
    #pragma unroll
    for (int j = 0; j < 2; ++j) {
      const int q = j * 512 + t;
      const int r = q >> 2;
      const int cc = ((q & 3) ^ ((r >> 1) & 3)) << 3;
      gload_lds16(gAb + (size_t)r * K + k0 + cc,
                  &lds[buf * BUFE + (j * 512 + (w << 6)) * 8]);
    }
    {
      const int q = t;
      const int r = q >> 2;
      const int cc = ((q & 3) ^ ((r >> 1) & 3)) << 3;
      gload_lds16(gBb + (size_t)r * K + k0 + cc,
                  &lds[buf * BUFE + 8192 + (w << 6) * 8]);
    }
  };
  const int csw = ((lo >> 1) & 3) << 3;
  auto compute = [&](int buf) {
    const ushort_t* as = &lds[buf * BUFE];
    const ushort_t* bs = &lds[buf * BUFE + 8192];
    bf16x8 af[4], bfr[4];
    #pragma unroll
    for (int mi = 0; mi < 4; ++mi)
      af[mi] = *(const bf16x8*)&as[(wm*64 + mi*16 + lo) * 32 + ((g*8) ^ csw)];
    #pragma unroll
    for (int ni = 0; ni < 4; ++ni)
      bfr[ni] = *(const bf16x8*)&bs[(wn*64 + ni*16 + lo) * 32 + ((g*8) ^ csw)];
    __builtin_amdgcn_s_setprio(1);
    #pragma unroll
    for (int mi = 0; mi < 4; ++mi)
      #pragma unroll
      for (int ni = 0; ni < 4; ++ni)
        acc[mi][ni] = __builtin_amdgcn_mfma_f32_16x16x32_bf16(af[mi], bfr[ni], acc[mi][ni], 0, 0, 0);
    __builtin_amdgcn_s_setprio(0);
  };

  const int NK = K >> 5;
  stage(0, 0); stage(1, 1); stage(2, 2);
  asm volatile("s_waitcnt vmcnt(6)" ::: "memory");
  __builtin_amdgcn_s_barrier();

  int buf = 0;
  #pragma unroll 1
  for (int kt = 0; kt < NK; ++kt) {
    compute(buf);
    asm volatile("s_waitcnt lgkmcnt(0)" ::: "memory");
    __builtin_amdgcn_s_barrier();
    if (kt + 3 < NK) {
      stage(kt + 3, buf);
      asm volatile("s_waitcnt vmcnt(6)" ::: "memory");
    } else if (kt + 2 < NK) {
      asm volatile("s_waitcnt vmcnt(3)" ::: "memory");
    } else {
      asm volatile("s_waitcnt vmcnt(0)" ::: "memory");
    }
    __builtin_amdgcn_s_barrier();
    buf = (buf == 2) ? 0 : buf + 1;
  }

  #pragma unroll
  for (int mi = 0; mi < 4; ++mi) {
    #pragma unroll
    for (int ni = 0; ni < 4; ++ni) {
      int colg = bn*128 + wn*64 + ni*16 + lo;
      if (colg < N) {
        float bv = bias ? bias[colg] : 0.f;
        #pragma unroll
        for (int i = 0; i < 4; ++i) {
          int rowg = bm*256 + wm*64 + mi*16 + 4*g + i;
          float vv = acc[mi][ni][i] + bv;
          if (MODE == 0) {
            ((float*)outp)[(size_t)rowg * N + colg] = vv;
          } else if (MODE == 2) {
            float ge = 0.5f * vv * (1.f + erff(vv * 0.70710678118f));
            ((ushort_t*)outp)[(size_t)rowg * N + colg] = f2bf(ge);
          } else {
            int which = colg / Cn;
            int rem = colg - which * Cn;
            int h = rem >> 6, d = rem & 63;
            int b = rowg >> 11, tt = rowg & (Tn - 1);
            ushort_t* qb = (ushort_t*)outp;
            size_t bh = (size_t)(b * Hn + h);
            size_t off = (bh * Tn + tt) * 64 + d;
            if (which == 0)      qb[off] = f2bf(vv * 0.125f);
            else if (which == 1) qb[QKV_ELEMS + off] = f2bf(vv);
            else                 qb[3*QKV_ELEMS + off] = f2bf(vv);   // staging; vtrans -> 2*QKV
          }
        }
      }
    }
  }
}

// ======== layer GEMM (aproj/mproj): 3-buf ring + T2 swizzle (64 tile, 4 waves) ========
template<int MODE, int TM>
__global__ __launch_bounds__(256) void gemm_kernel(
    const ushort_t* __restrict__ A, const ushort_t* __restrict__ Bt,
    const float* __restrict__ bias, void* __restrict__ outp,
    const float* __restrict__ res, int M, int N, int K) {
  constexpr int MI = TM / 32;
  constexpr int ASZ = TM * 32;
  constexpr int BUFE = ASZ + 4096;
  constexpr int LPT = TM/64 + 2;
  __shared__ ushort_t lds[3 * BUFE];
  const int t = threadIdx.x;
  int bm, bn;
  {
    int seq = swz_lin();
    const int G = 8;
    int gsz = G * gridDim.y;
    int grp = seq / gsz;
    int t2 = seq - grp * gsz;
    bn = t2 / G;
    bm = grp * G + (t2 - bn * G);
  }
  const int w = t >> 6, l = t & 63, lo = l & 15, g = l >> 4;
  const int wm = w >> 1, wn = w & 1;

  f32x4 acc[MI][4];
  #pragma unroll
  for (int i = 0; i < MI; ++i)
    #pragma unroll
    for (int j = 0; j < 4; ++j) acc[i][j] = zero4();

  const ushort_t* gAb = A  + (size_t)bm * TM * K;
  const ushort_t* gBb = Bt + (size_t)bn * 128 * K;

  auto stage = [&](int kt, int buf) {
    const int k0 = kt << 5;
    #pragma unroll
    for (int j = 0; j < TM/64; ++j) {
      const int q = j * 256 + t;
      const int r = q >> 2;
      const int cc = ((q & 3) ^ ((r >> 1) & 3)) << 3;
      gload_lds16(gAb + (size_t)r * K + k0 + cc, &lds[buf*BUFE + (j*256 + w*64)*8]);
    }
    #pragma unroll
    for (int j = 0; j < 2; ++j) {
      const int q = j * 256 + t;
      const int r = q >> 2;
      const int cc = ((q & 3) ^ ((r >> 1) & 3)) << 3;
      gload_lds16(gBb + (size_t)r * K + k0 + cc, &lds[buf*BUFE + ASZ + (j*256 + w*64)*8]);
    }
  };
  const int csw = ((lo >> 1) & 3) << 3;
  auto compute = [&](int buf) {
    const ushort_t* as = &lds[buf * BUFE];
    const ushort_t* bs = &lds[buf * BUFE + ASZ];
    bf16x8 af[MI], bfr[4];
    #pragma unroll
    for (int mi = 0; mi < MI; ++mi)
      af[mi] = *(const bf16x8*)&as[(wm*(TM/2) + mi*16 + lo) * 32 + ((g*8) ^ csw)];
    #pragma unroll
    for (int ni = 0; ni < 4; ++ni)
      bfr[ni] = *(const bf16x8*)&bs[(wn*64 + ni*16 + lo) * 32 + ((g*8) ^ csw)];
    __builtin_amdgcn_s_setprio(1);
    #pragma unroll
    for (int mi = 0; mi < MI; ++mi)
      #pragma unroll
      for (int ni = 0; ni < 4; ++ni)
        acc[mi][ni] = __builtin_amdgcn_mfma_f32_16x16x32_bf16(af[mi], bfr[ni], acc[mi][ni], 0, 0, 0);
    __builtin_amdgcn_s_setprio(0);
  };

  const int NK = K >> 5;
  stage(0, 0); stage(1, 1); stage(2, 2);
  if constexpr (LPT == 4) asm volatile("s_waitcnt vmcnt(8)" ::: "memory");
  else                    asm volatile("s_waitcnt vmcnt(6)" ::: "memory");
  __builtin_amdgcn_s_barrier();

  int buf = 0;
  #pragma unroll 1
  for (int kt = 0; kt < NK; ++kt) {
    compute(buf);
    asm volatile("s_waitcnt lgkmcnt(0)" ::: "memory");
    __builtin_amdgcn_s_barrier();
    if (kt + 3 < NK) {
      stage(kt + 3, buf);
      if constexpr (LPT == 4) asm volatile("s_waitcnt vmcnt(8)" ::: "memory");
      else                    asm volatile("s_waitcnt vmcnt(6)" ::: "memory");
    } else if (kt + 2 < NK) {
      if constexpr (LPT == 4) asm volatile("s_waitcnt vmcnt(4)" ::: "memory");
      else                    asm volatile("s_waitcnt vmcnt(3)" ::: "memory");
    } else {
      asm volatile("s_waitcnt vmcnt(0)" ::: "memory");
    }
    __builtin_amdgcn_s_barrier();
    buf = (buf == 2) ? 0 : buf + 1;
  }

  #pragma unroll
  for (int mi = 0; mi < MI; ++mi) {
    #pragma unroll
    for (int ni = 0; ni < 4; ++ni) {
      int colg = bn*128 + wn*64 + ni*16 + lo;
      if (colg < N) {
        float bv = bias ? bias[colg] : 0.f;
        #pragma unroll
        for (int i = 0; i < 4; ++i) {
          int rowg = bm*TM + wm*(TM/2) + mi*16 + 4*g + i;
          size_t off = (size_t)rowg * N + colg;
          float vv = acc[mi][ni][i] + bv;
          ((float*)outp)[off] = res[off] + vv;
        }
      }
    }
  }
}

// ---------------- flash attention (causal), 1 wave / 32 q-rows (2 halves share K/V) ----------------
__global__ __launch_bounds__(64) void attn_kernel(const ushort_t* __restrict__ qkvh,
                                                  ushort_t* __restrict__ y) {
  const int l = threadIdx.x;
  const int lo = l & 15, g = l >> 4;
  int nl = swz_lin();
  const int qt = 63 - (nl & 63);
  const int bh = nl >> 6;
  const int b = bh / Hn, h = bh % Hn;
  const int q0 = qt * 32;
  const ushort_t* Qp = qkvh + (size_t)bh * Tn * 64;
  const ushort_t* Kp = qkvh + QKV_ELEMS + (size_t)bh * Tn * 64;
  const ushort_t* Vt = qkvh + 2*QKV_ELEMS + (size_t)bh * 64 * Tn;

  bf16x8 qf0[2], qf1[2];
  #pragma unroll
  for (int ch = 0; ch < 2; ++ch) {
    qf0[ch] = *(const bf16x8*)&Qp[(size_t)(q0 + lo) * 64 + ch*32 + g*8];
    qf1[ch] = *(const bf16x8*)&Qp[(size_t)(q0 + 16 + lo) * 64 + ch*32 + g*8];
  }

  f32x4 of0[4], of1[4];
  #pragma unroll
  for (int ch = 0; ch < 4; ++ch) { of0[ch] = zero4(); of1[ch] = zero4(); }
  float m0 = -1e30f, m1 = -1e30f, ls0 = 0.f, ls1 = 0.f;
  const int nkv = q0 + 32;
  const bool ghi = (g >= 2);
  const int lg2 = (g & 1) * 32;

  for (int kv0 = 0; kv0 < nkv; kv0 += 32) {
    bf16x8 vf[4];
    #pragma unroll
    for (int ch = 0; ch < 4; ++ch)
      vf[ch] = *(const bf16x8*)&Vt[(size_t)(ch*16 + lo) * Tn + kv0 + g*8];

    float s80[8], s81[8];
    #pragma unroll
    for (int sub = 0; sub < 2; ++sub) {
      int kvb = kv0 + 16*sub;
      bf16x8 kf[2];
      #pragma unroll
      for (int ch = 0; ch < 2; ++ch)
        kf[ch] = *(const bf16x8*)&Kp[(size_t)(kvb + lo) * 64 + ch*32 + g*8];
      f32x4 st0 = zero4(), st1 = zero4();
      st0 = __builtin_amdgcn_mfma_f32_16x16x32_bf16(kf[0], qf0[0], st0, 0, 0, 0);
      st0 = __builtin_amdgcn_mfma_f32_16x16x32_bf16(kf[1], qf0[1], st0, 0, 0, 0);
      st1 = __builtin_amdgcn_mfma_f32_16x16x32_bf16(kf[0], qf1[0], st1, 0, 0, 0);
      st1 = __builtin_amdgcn_mfma_f32_16x16x32_bf16(kf[1], qf1[1], st1, 0, 0, 0);
      #pragma unroll
      for (int i = 0; i < 4; ++i) {
        int kvi = kvb + 4*g + i;
        s80[sub*4 + i] = (kvi <= q0 + lo)      ? st0[i] : -1e30f;
        s81[sub*4 + i] = (kvi <= q0 + 16 + lo) ? st1[i] : -1e30f;
      }
    }
    {
      float tmax = s80[0];
      #pragma unroll
      for (int j = 1; j < 8; ++j) tmax = fmaxf(tmax, s80[j]);
      tmax = fmaxf(tmax, __shfl_xor(tmax, 16));
      tmax = fmaxf(tmax, __shfl_xor(tmax, 32));
      if (!__all(tmax <= m0)) {
        float newm = fmaxf(m0, tmax);
        float resc = __expf(m0 - newm);
        ls0 *= resc; m0 = newm;
        #pragma unroll
        for (int i = 0; i < 4; ++i) {
          float rs = __shfl(resc, 4*g + i);
          of0[0][i] *= rs; of0[1][i] *= rs; of0[2][i] *= rs; of0[3][i] *= rs;
        }
      }
    }
    {
      float tmax = s81[0];
      #pragma unroll
      for (int j = 1; j < 8; ++j) tmax = fmaxf(tmax, s81[j]);
      tmax = fmaxf(tmax, __shfl_xor(tmax, 16));
      tmax = fmaxf(tmax, __shfl_xor(tmax, 32));
      if (!__all(tmax <= m1)) {
        float newm = fmaxf(m1, tmax);
        float resc = __expf(m1 - newm);
        ls1 *= resc; m1 = newm;
        #pragma unroll
        for (int i = 0; i < 4; ++i) {
          float rs = __shfl(resc, 4*g + i);
          of1[0][i] *= rs; of1[1][i] *= rs; of1[2][i] *= rs; of1[3][i] *= rs;
        }
      }
    }
    float p80[8], p81[8]; float ps0 = 0.f, ps1 = 0.f;
    #pragma unroll
    for (int j = 0; j < 8; ++j) {
      p80[j] = __expf(s80[j] - m0); ps0 += p80[j];
      p81[j] = __expf(s81[j] - m1); ps1 += p81[j];
    }
    ps0 += __shfl_xor(ps0, 16); ps0 += __shfl_xor(ps0, 32); ls0 += ps0;
    ps1 += __shfl_xor(ps1, 16); ps1 += __shfl_xor(ps1, 32); ls1 += ps1;
    unsigned int q40[4], q41[4];
    #pragma unroll
    for (int c = 0; c < 4; ++c) {
      asm("v_cvt_pk_bf16_f32 %0, %1, %2" : "=v"(q40[c]) : "v"(p80[2*c]), "v"(p80[2*c+1]));
      asm("v_cvt_pk_bf16_f32 %0, %1, %2" : "=v"(q41[c]) : "v"(p81[2*c]), "v"(p81[2*c+1]));
    }
    union U { unsigned int wv[4]; bf16x8 v; } pu0, pu1;
    #pragma unroll
    for (int j = 0; j < 4; ++j) {
      int srcLane = lo + lg2 + ((j >> 1) << 4);
      unsigned int lo_w0 = (unsigned int)__shfl((int)q40[j & 1], srcLane);
      unsigned int hi_w0 = (unsigned int)__shfl((int)q40[2 + (j & 1)], srcLane);
      pu0.wv[j] = ghi ? hi_w0 : lo_w0;
      unsigned int lo_w1 = (unsigned int)__shfl((int)q41[j & 1], srcLane);
      unsigned int hi_w1 = (unsigned int)__shfl((int)q41[2 + (j & 1)], srcLane);
      pu1.wv[j] = ghi ? hi_w1 : lo_w1;
    }
    #pragma unroll
    for (int ch = 0; ch < 4; ++ch) {
      of0[ch] = __builtin_amdgcn_mfma_f32_16x16x32_bf16(pu0.v, vf[ch], of0[ch], 0, 0, 0);
      of1[ch] = __builtin_amdgcn_mfma_f32_16x16x32_bf16(pu1.v, vf[ch], of1[ch], 0, 0, 0);
    }
  }

  #pragma unroll
  for (int i = 0; i < 4; ++i) {
    float li0 = 1.f / __shfl(ls0, 4*g + i);
    float li1 = 1.f / __shfl(ls1, 4*g + i);
    of0[0][i] *= li0; of0[1][i] *= li0; of0[2][i] *= li0; of0[3][i] *= li0;
    of1[0][i] *= li1; of1[1][i] *= li1; of1[2][i] *= li1; of1[3][i] *= li1;
  }
  ushort_t* yb = y + ((size_t)b*Tn + q0) * Cn + h*64;
  #pragma unroll
  for (int ch = 0; ch < 4; ++ch)
    #pragma unroll
    for (int i = 0; i < 4; ++i) {
      yb[(size_t)(4*g + i) * Cn + ch*16 + lo] = f2bf(of0[ch][i]);
      yb[(size_t)(16 + 4*g + i) * Cn + ch*16 + lo] = f2bf(of1[ch][i]);
    }
}

// ---------------- launch ----------------
extern "C" void kernel_launch(void* const* d_in, const int* in_sizes, int n_in,
                              void* d_out, int out_size, void* d_ws, size_t ws_size,
                              hipStream_t stream) {
  const int*   idx     = (const int*)d_in[0];
  const float* tok_emb = (const float*)d_in[1];
  const float* pos_emb = (const float*)d_in[2];
  const float* ln1_g   = (const float*)d_in[3];
  const float* ln1_b   = (const float*)d_in[4];
  const float* qkv_w   = (const float*)d_in[5];
  const float* qkv_b   = (const float*)d_in[6];
  const float* aproj_w = (const float*)d_in[7];
  const float* aproj_b = (const float*)d_in[8];
  const float* ln2_g   = (const float*)d_in[9];
  const float* ln2_b   = (const float*)d_in[10];
  const float* fc_w    = (const float*)d_in[11];
  const float* fc_b    = (const float*)d_in[12];
  const float* mproj_w = (const float*)d_in[13];
  const float* mproj_b = (const float*)d_in[14];
  const float* lnf_g   = (const float*)d_in[15];
  const float* lnf_b   = (const float*)d_in[16];
  const float* head_w  = (const float*)d_in[17];
  float* out = (float*)d_out;

  char* ws = (char*)d_ws;
  float*    x    = (float*)(ws);                         // 12,582,912 B
  ushort_t* hA   = (ushort_t*)(ws + 12582912);           //  6,291,456 B
  ushort_t* hB   = (ushort_t*)(ws + 18874368);           // 25,165,824 B
  ushort_t* qkvh = (ushort_t*)(ws + 44040192);           // 25,165,824 B (q,k,vT,vtmp)
  ushort_t* wT   = (ushort_t*)(ws + 69206016);           // 77,463,552 B (4-layer pack / head Npad 50432)

  const int M = Bn * Tn;  // 4096
  dim3 tb(32, 8);

  embed_kernel<<<M, 192, 0, stream>>>(idx, tok_emb, pos_emb, x);
  tcvtAll_kernel<<<27648, tb, 0, stream>>>(qkv_w, aproj_w, fc_w, mproj_w, wT);
  for (int l = 0; l < Ln; ++l) {
    ushort_t* wTl = wT + (size_t)l * PACK_SZ;
    ln_kernel<<<M/4, 256, 0, stream>>>(x, ln1_g + l*Cn, ln1_b + l*Cn, hA);
    gemm256_kernel<3><<<dim3(M/256, 2304/128), 512, 0, stream>>>(hA, wTl + OFF_QKV, qkv_b + (size_t)l*3*Cn, qkvh, M, 2304, 768);
    vtrans_kernel<<<dim3(Tn/64, Bn*Hn), 256, 0, stream>>>(qkvh + 3*QKV_ELEMS, qkvh + 2*QKV_ELEMS);
    attn_kernel<<<dim3(64, Bn*Hn), 64, 0, stream>>>(qkvh, hA);
    gemm_kernel<1,64><<<dim3(M/64, 768/128), 256, 0, stream>>>(hA, wTl + OFF_APROJ, aproj_b + (size_t)l*Cn, x, x, M, 768, 768);
    ln_kernel<<<M/4, 256, 0, stream>>>(x, ln2_g + l*Cn, ln2_b + l*Cn, hA);
    gemm256_kernel<2><<<dim3(M/256, 3072/128), 512, 0, stream>>>(hA, wTl + OFF_FC, fc_b + (size_t)l*4*Cn, hB, M, 3072, 768);
    gemm_kernel<1,64><<<dim3(M/64, 768/128), 256, 0, stream>>>(hB, wTl + OFF_MPROJ, mproj_b + (size_t)l*Cn, x, x, M, 768, 3072);
  }
  ln_kernel<<<M/4, 256, 0, stream>>>(x, lnf_g, lnf_b, hA);
  tcvt_kernel<<<dim3(50432/32, 768/32), tb, 0, stream>>>(head_w, wT, 768, Vn, 50432);
  gemm256_kernel<0><<<dim3(M/256, 50432/128), 512, 0, stream>>>(hA, wT, nullptr, out, M, Vn, 768);
}

// Round 18
// 1536.081 us; speedup vs baseline: 1.0018x; 1.0018x over previous
//
#include <hip/hip_runtime.h>
#include <cstdint>
#include <cstddef>

#define Tn 2048
#define Bn 2
#define Hn 12
#define Cn 768
#define Ln 4
#define Vn 50257

typedef unsigned short ushort_t;
typedef __attribute__((ext_vector_type(8))) __bf16 bf16x8;
typedef __attribute__((ext_vector_type(8))) unsigned short u16x8;
typedef __attribute__((ext_vector_type(4))) unsigned short u16x4;
typedef __attribute__((ext_vector_type(4))) float f32x4;

static constexpr size_t QKV_ELEMS = (size_t)Bn * Hn * Tn * 64;  // 3,145,728
static constexpr size_t OFF_QKV = 0;
static constexpr size_t OFF_APROJ = 1769472;
static constexpr size_t OFF_FC = 2359296;
static constexpr size_t OFF_MPROJ = 4718592;
static constexpr size_t PACK_SZ = 7077888;

__device__ inline unsigned short f2bf(float f) {
  unsigned int u = __float_as_uint(f);
  unsigned int r = (u + 0x7fffu + ((u >> 16) & 1u)) >> 16;
  return (unsigned short)r;
}

__device__ inline f32x4 zero4() { f32x4 z; z[0]=0.f; z[1]=0.f; z[2]=0.f; z[3]=0.f; return z; }

__device__ inline void gload_lds16(const ushort_t* g, ushort_t* l) {
  __builtin_amdgcn_global_load_lds(
      (const __attribute__((address_space(1))) void*)g,
      (__attribute__((address_space(3))) void*)l, 16, 0, 0);
}

// bijective XCD-chunked swizzle (m204)
__device__ inline int swz_lin() {
  int nbm = gridDim.x;
  int lin = blockIdx.y * nbm + blockIdx.x;
  int nwg = nbm * gridDim.y;
  int q = nwg >> 3, r = nwg & 7, x = lin & 7, p = lin >> 3;
  return (x < r ? x * (q + 1) : r * (q + 1) + (x - r) * q) + p;
}

// ---------------- embedding (float4) ----------------
__global__ __launch_bounds__(192) void embed_kernel(const int* __restrict__ idx,
    const float* __restrict__ tok, const float* __restrict__ pos, float* __restrict__ x) {
  int row = blockIdx.x;
  int t = row & (Tn - 1);
  int token = idx[row];
  const f32x4* tr = (const f32x4*)(tok + (size_t)token * Cn);
  const f32x4* pr = (const f32x4*)(pos + (size_t)t * Cn);
  f32x4* xr = (f32x4*)(x + (size_t)row * Cn);
  xr[threadIdx.x] = tr[threadIdx.x] + pr[threadIdx.x];
}

// ---------------- layernorm -> bf16 (wave per row, float4) ----------------
__global__ __launch_bounds__(256) void ln_kernel(const float* __restrict__ x,
    const float* __restrict__ gam, const float* __restrict__ bet, ushort_t* __restrict__ out) {
  const int wv = threadIdx.x >> 6, lane = threadIdx.x & 63;
  const int row = blockIdx.x * 4 + wv;
  const f32x4* xr = (const f32x4*)(x + (size_t)row * Cn);
  f32x4 v[3]; float s = 0.f, s2 = 0.f;
  #pragma unroll
  for (int e = 0; e < 3; ++e) {
    v[e] = xr[lane + e*64];
    #pragma unroll
    for (int j = 0; j < 4; ++j) { s += v[e][j]; s2 += v[e][j]*v[e][j]; }
  }
  #pragma unroll
  for (int off = 32; off >= 1; off >>= 1) { s += __shfl_xor(s, off); s2 += __shfl_xor(s2, off); }
  float mean = s * (1.f / Cn);
  float var  = s2 * (1.f / Cn) - mean * mean;
  float rstd = rsqrtf(var + 1e-5f);
  const f32x4* g4 = (const f32x4*)gam;
  const f32x4* b4 = (const f32x4*)bet;
  u16x4* o4 = (u16x4*)(out + (size_t)row * Cn);
  #pragma unroll
  for (int e = 0; e < 3; ++e) {
    f32x4 gv = g4[lane + e*64], bv = b4[lane + e*64];
    u16x4 o;
    #pragma unroll
    for (int j = 0; j < 4; ++j) o[j] = f2bf((v[e][j] - mean) * rstd * gv[j] + bv[j]);
    o4[lane + e*64] = o;
  }
}

// ---------------- transpose + f32->bf16 (head weight) ----------------
__global__ __launch_bounds__(256) void tcvt_kernel(const float* __restrict__ in,
    ushort_t* __restrict__ out, int K, int N, int Npad) {
  __shared__ float tile[32][33];
  int n0 = blockIdx.x * 32, k0 = blockIdx.y * 32;
  int tx = threadIdx.x, ty = threadIdx.y;
  #pragma unroll
  for (int r = 0; r < 4; ++r) {
    int k = k0 + ty + 8*r;
    int n = n0 + tx;
    tile[ty + 8*r][tx] = (n < N) ? in[(size_t)k * N + n] : 0.f;
  }
  __syncthreads();
  #pragma unroll
  for (int r = 0; r < 4; ++r) {
    int n = n0 + ty + 8*r;
    out[(size_t)n * K + k0 + tx] = f2bf(tile[tx][ty + 8*r]);
  }
}

// ---------------- ALL layers' weight transpose+convert (one launch) ----------------
__global__ __launch_bounds__(256) void tcvtAll_kernel(const float* __restrict__ qkvw,
    const float* __restrict__ aprojw, const float* __restrict__ fcw,
    const float* __restrict__ mprojw, ushort_t* __restrict__ wT) {
  __shared__ float tile[32][33];
  int bid = blockIdx.x;
  const int layer = bid / 6912;
  int local = bid - layer * 6912;
  const float* in; int K, N, tilesX; size_t ooff;
  if (local < 1728)      { in = qkvw   + (size_t)layer*1769472; K = 768;  N = 2304; tilesX = 72; ooff = OFF_QKV; }
  else if (local < 2304) { in = aprojw + (size_t)layer*589824;  K = 768;  N = 768;  tilesX = 24; ooff = OFF_APROJ; local -= 1728; }
  else if (local < 4608) { in = fcw    + (size_t)layer*2359296; K = 768;  N = 3072; tilesX = 96; ooff = OFF_FC;    local -= 2304; }
  else                   { in = mprojw + (size_t)layer*2359296; K = 3072; N = 768;  tilesX = 24; ooff = OFF_MPROJ; local -= 4608; }
  int n0 = (local % tilesX) * 32, k0 = (local / tilesX) * 32;
  int tx = threadIdx.x, ty = threadIdx.y;
  ushort_t* out = wT + (size_t)layer * PACK_SZ + ooff;
  #pragma unroll
  for (int r = 0; r < 4; ++r)
    tile[ty + 8*r][tx] = in[(size_t)(k0 + ty + 8*r) * N + n0 + tx];
  __syncthreads();
  #pragma unroll
  for (int r = 0; r < 4; ++r)
    out[(size_t)(n0 + ty + 8*r) * K + k0 + tx] = f2bf(tile[tx][ty + 8*r]);
}

// ---------------- bf16 64x64 tile transpose: [BH,T,64] -> [BH,64,T] ----------------
__global__ __launch_bounds__(256) void vtrans_kernel(const ushort_t* __restrict__ vin,
                                                     ushort_t* __restrict__ vout) {
  __shared__ ushort_t tile[64][65];
  int t0 = blockIdx.x * 64;
  size_t bh = blockIdx.y;
  const ushort_t* src = vin + (bh * Tn + t0) * 64;
  int row = threadIdx.x >> 2, c0 = (threadIdx.x & 3) * 16;
  u16x8 a = *(const u16x8*)&src[(size_t)row * 64 + c0];
  u16x8 b = *(const u16x8*)&src[(size_t)row * 64 + c0 + 8];
  #pragma unroll
  for (int j = 0; j < 8; ++j) { tile[row][c0 + j] = a[j]; tile[row][c0 + 8 + j] = b[j]; }
  __syncthreads();
  int d = threadIdx.x >> 2, tq = (threadIdx.x & 3) * 16;
  u16x8 o0, o1;
  #pragma unroll
  for (int j = 0; j < 8; ++j) { o0[j] = tile[tq + j][d]; o1[j] = tile[tq + 8 + j][d]; }
  ushort_t* dst = vout + (bh * 64 + d) * Tn + t0 + tq;
  *(u16x8*)&dst[0] = o0;
  *(u16x8*)&dst[8] = o1;
}

// ======== 256x128 8-wave GEMM: 3-buf ring (72KB -> 2 blocks/CU) + T2 swizzle, G=4 ========
// MODE 0: f32 = acc+bias ; 2: bf16 = gelu(acc+bias) ; 3: qkv scatter
template<int MODE>
__global__ __launch_bounds__(512) void gemm256_kernel(
    const ushort_t* __restrict__ A, const ushort_t* __restrict__ Bt,
    const float* __restrict__ bias, void* __restrict__ outp,
    int M, int N, int K) {
  constexpr int BUFE = 12288;
  __shared__ ushort_t lds[3 * BUFE];
  const int t = threadIdx.x;
  const int w = t >> 6, l = t & 63, lo = l & 15, g = l >> 4;
  const int wm = w >> 1, wn = w & 1;

  int bm, bn;
  {
    int seq = swz_lin();
    int gsz = 4 * gridDim.y;
    int grp = seq / gsz;
    int t2 = seq - grp * gsz;
    bn = t2 >> 2;
    bm = grp * 4 + (t2 & 3);
  }

  const ushort_t* gAb = A  + (size_t)bm * 256 * K;
  const ushort_t* gBb = Bt + (size_t)bn * 128 * K;

  f32x4 acc[4][4];
  #pragma unroll
  for (int i = 0; i < 4; ++i)
    #pragma unroll
    for (int j = 0; j < 4; ++j) acc[i][j] = zero4();

  auto stage = [&](int kt, int buf) {
    const int k0 = kt << 5;
    #pragma unroll
    for (int j = 0; j < 2; ++j) {
      const int q = j * 512 + t;
      const int r = q >> 2;
      const int cc = ((q & 3) ^ ((r >> 1) & 3)) << 3;
      gload_lds16(gAb + (size_t)r * K + k0 + cc,
                  &lds[buf * BUFE + (j * 512 + (w << 6)) * 8]);
    }
    {
      const int q = t;
      const int r = q >> 2;
      const int cc = ((q & 3) ^ ((r >> 1) & 3)) << 3;
      gload_lds16(gBb + (size_t)r * K + k0 + cc,
                  &lds[buf * BUFE + 8192 + (w << 6) * 8]);
    }
  };
  const int csw = ((lo >> 1) & 3) << 3;
  auto compute = [&](int buf) {
    const ushort_t* as = &lds[buf * BUFE];
    const ushort_t* bs = &lds[buf * BUFE + 8192];
    bf16x8 af[4], bfr[4];
    #pragma unroll
    for (int mi = 0; mi < 4; ++mi)
      af[mi] = *(const bf16x8*)&as[(wm*64 + mi*16 + lo) * 32 + ((g*8) ^ csw)];
    #pragma unroll
    for (int ni = 0; ni < 4; ++ni)
      bfr[ni] = *(const bf16x8*)&bs[(wn*64 + ni*16 + lo) * 32 + ((g*8) ^ csw)];
    __builtin_amdgcn_s_setprio(1);
    #pragma unroll
    for (int mi = 0; mi < 4; ++mi)
      #pragma unroll
      for (int ni = 0; ni < 4; ++ni)
        acc[mi][ni] = __builtin_amdgcn_mfma_f32_16x16x32_bf16(af[mi], bfr[ni], acc[mi][ni], 0, 0, 0);
    __builtin_amdgcn_s_setprio(0);
  };

  const int NK = K >> 5;
  stage(0, 0); stage(1, 1); stage(2, 2);
  asm volatile("s_waitcnt vmcnt(6)" ::: "memory");
  __builtin_amdgcn_s_barrier();

  int buf = 0;
  #pragma unroll 1
  for (int kt = 0; kt < NK; ++kt) {
    compute(buf);
    asm volatile("s_waitcnt lgkmcnt(0)" ::: "memory");
    __builtin_amdgcn_s_barrier();
    if (kt + 3 < NK) {
      stage(kt + 3, buf);
      asm volatile("s_waitcnt vmcnt(6)" ::: "memory");
    } else if (kt + 2 < NK) {
      asm volatile("s_waitcnt vmcnt(3)" ::: "memory");
    } else {
      asm volatile("s_waitcnt vmcnt(0)" ::: "memory");
    }
    __builtin_amdgcn_s_barrier();
    buf = (buf == 2) ? 0 : buf + 1;
  }

  #pragma unroll
  for (int mi = 0; mi < 4; ++mi) {
    #pragma unroll
    for (int ni = 0; ni < 4; ++ni) {
      int colg = bn*128 + wn*64 + ni*16 + lo;
      if (colg < N) {
        float bv = bias ? bias[colg] : 0.f;
        #pragma unroll
        for (int i = 0; i < 4; ++i) {
          int rowg = bm*256 + wm*64 + mi*16 + 4*g + i;
          float vv = acc[mi][ni][i] + bv;
          if (MODE == 0) {
            ((float*)outp)[(size_t)rowg * N + colg] = vv;
          } else if (MODE == 2) {
            float ge = 0.5f * vv * (1.f + erff(vv * 0.70710678118f));
            ((ushort_t*)outp)[(size_t)rowg * N + colg] = f2bf(ge);
          } else {
            int which = colg / Cn;
            int rem = colg - which * Cn;
            int h = rem >> 6, d = rem & 63;
            int b = rowg >> 11, tt = rowg & (Tn - 1);
            ushort_t* qb = (ushort_t*)outp;
            size_t bh = (size_t)(b * Hn + h);
            size_t off = (bh * Tn + tt) * 64 + d;
            if (which == 0)      qb[off] = f2bf(vv * 0.125f);
            else if (which == 1) qb[QKV_ELEMS + off] = f2bf(vv);
            else                 qb[3*QKV_ELEMS + off] = f2bf(vv);   // staging; vtrans -> 2*QKV
          }
        }
      }
    }
  }
}

// ======== layer GEMM (aproj/mproj): 3-buf ring + T2 swizzle (64 tile, 4 waves), G=4 ========
template<int MODE, int TM>
__global__ __launch_bounds__(256) void gemm_kernel(
    const ushort_t* __restrict__ A, const ushort_t* __restrict__ Bt,
    const float* __restrict__ bias, void* __restrict__ outp,
    const float* __restrict__ res, int M, int N, int K) {
  constexpr int MI = TM / 32;
  constexpr int ASZ = TM * 32;
  constexpr int BUFE = ASZ + 4096;
  constexpr int LPT = TM/64 + 2;
  __shared__ ushort_t lds[3 * BUFE];
  const int t = threadIdx.x;
  int bm, bn;
  {
    int seq = swz_lin();
    const int G = 4;            // G=8 -> 4: per-XCD A hot-set 3.1MB -> 1.57MB (K=3072 case), L2-fit
    int gsz = G * gridDim.y;
    int grp = seq / gsz;
    int t2 = seq - grp * gsz;
    bn = t2 / G;
    bm = grp * G + (t2 - bn * G);
  }
  const int w = t >> 6, l = t & 63, lo = l & 15, g = l >> 4;
  const int wm = w >> 1, wn = w & 1;

  f32x4 acc[MI][4];
  #pragma unroll
  for (int i = 0; i < MI; ++i)
    #pragma unroll
    for (int j = 0; j < 4; ++j) acc[i][j] = zero4();

  const ushort_t* gAb = A  + (size_t)bm * TM * K;
  const ushort_t* gBb = Bt + (size_t)bn * 128 * K;

  auto stage = [&](int kt, int buf) {
    const int k0 = kt << 5;
    #pragma unroll
    for (int j = 0; j < TM/64; ++j) {
      const int q = j * 256 + t;
      const int r = q >> 2;
      const int cc = ((q & 3) ^ ((r >> 1) & 3)) << 3;
      gload_lds16(gAb + (size_t)r * K + k0 + cc, &lds[buf*BUFE + (j*256 + w*64)*8]);
    }
    #pragma unroll
    for (int j = 0; j < 2; ++j) {
      const int q = j * 256 + t;
      const int r = q >> 2;
      const int cc = ((q & 3) ^ ((r >> 1) & 3)) << 3;
      gload_lds16(gBb + (size_t)r * K + k0 + cc, &lds[buf*BUFE + ASZ + (j*256 + w*64)*8]);
    }
  };
  const int csw = ((lo >> 1) & 3) << 3;
  auto compute = [&](int buf) {
    const ushort_t* as = &lds[buf * BUFE];
    const ushort_t* bs = &lds[buf * BUFE + ASZ];
    bf16x8 af[MI], bfr[4];
    #pragma unroll
    for (int mi = 0; mi < MI; ++mi)
      af[mi] = *(const bf16x8*)&as[(wm*(TM/2) + mi*16 + lo) * 32 + ((g*8) ^ csw)];
    #pragma unroll
    for (int ni = 0; ni < 4; ++ni)
      bfr[ni] = *(const bf16x8*)&bs[(wn*64 + ni*16 + lo) * 32 + ((g*8) ^ csw)];
    __builtin_amdgcn_s_setprio(1);
    #pragma unroll
    for (int mi = 0; mi < MI; ++mi)
      #pragma unroll
      for (int ni = 0; ni < 4; ++ni)
        acc[mi][ni] = __builtin_amdgcn_mfma_f32_16x16x32_bf16(af[mi], bfr[ni], acc[mi][ni], 0, 0, 0);
    __builtin_amdgcn_s_setprio(0);
  };

  const int NK = K >> 5;
  stage(0, 0); stage(1, 1); stage(2, 2);
  if constexpr (LPT == 4) asm volatile("s_waitcnt vmcnt(8)" ::: "memory");
  else                    asm volatile("s_waitcnt vmcnt(6)" ::: "memory");
  __builtin_amdgcn_s_barrier();

  int buf = 0;
  #pragma unroll 1
  for (int kt = 0; kt < NK; ++kt) {
    compute(buf);
    asm volatile("s_waitcnt lgkmcnt(0)" ::: "memory");
    __builtin_amdgcn_s_barrier();
    if (kt + 3 < NK) {
      stage(kt + 3, buf);
      if constexpr (LPT == 4) asm volatile("s_waitcnt vmcnt(8)" ::: "memory");
      else                    asm volatile("s_waitcnt vmcnt(6)" ::: "memory");
    } else if (kt + 2 < NK) {
      if constexpr (LPT == 4) asm volatile("s_waitcnt vmcnt(4)" ::: "memory");
      else                    asm volatile("s_waitcnt vmcnt(3)" ::: "memory");
    } else {
      asm volatile("s_waitcnt vmcnt(0)" ::: "memory");
    }
    __builtin_amdgcn_s_barrier();
    buf = (buf == 2) ? 0 : buf + 1;
  }

  #pragma unroll
  for (int mi = 0; mi < MI; ++mi) {
    #pragma unroll
    for (int ni = 0; ni < 4; ++ni) {
      int colg = bn*128 + wn*64 + ni*16 + lo;
      if (colg < N) {
        float bv = bias ? bias[colg] : 0.f;
        #pragma unroll
        for (int i = 0; i < 4; ++i) {
          int rowg = bm*TM + wm*(TM/2) + mi*16 + 4*g + i;
          size_t off = (size_t)rowg * N + colg;
          float vv = acc[mi][ni][i] + bv;
          ((float*)outp)[off] = res[off] + vv;
        }
      }
    }
  }
}

// ---------------- flash attention (causal), 1 wave / 32 q-rows (2 halves share K/V) ----------------
__global__ __launch_bounds__(64) void attn_kernel(const ushort_t* __restrict__ qkvh,
                                                  ushort_t* __restrict__ y) {
  const int l = threadIdx.x;
  const int lo = l & 15, g = l >> 4;
  int nl = swz_lin();
  const int qt = 63 - (nl & 63);
  const int bh = nl >> 6;
  const int b = bh / Hn, h = bh % Hn;
  const int q0 = qt * 32;
  const ushort_t* Qp = qkvh + (size_t)bh * Tn * 64;
  const ushort_t* Kp = qkvh + QKV_ELEMS + (size_t)bh * Tn * 64;
  const ushort_t* Vt = qkvh + 2*QKV_ELEMS + (size_t)bh * 64 * Tn;

  bf16x8 qf0[2], qf1[2];
  #pragma unroll
  for (int ch = 0; ch < 2; ++ch) {
    qf0[ch] = *(const bf16x8*)&Qp[(size_t)(q0 + lo) * 64 + ch*32 + g*8];
    qf1[ch] = *(const bf16x8*)&Qp[(size_t)(q0 + 16 + lo) * 64 + ch*32 + g*8];
  }

  f32x4 of0[4], of1[4];
  #pragma unroll
  for (int ch = 0; ch < 4; ++ch) { of0[ch] = zero4(); of1[ch] = zero4(); }
  float m0 = -1e30f, m1 = -1e30f, ls0 = 0.f, ls1 = 0.f;
  const int nkv = q0 + 32;
  const bool ghi = (g >= 2);
  const int lg2 = (g & 1) * 32;

  for (int kv0 = 0; kv0 < nkv; kv0 += 32) {
    bf16x8 vf[4];
    #pragma unroll
    for (int ch = 0; ch < 4; ++ch)
      vf[ch] = *(const bf16x8*)&Vt[(size_t)(ch*16 + lo) * Tn + kv0 + g*8];

    float s80[8], s81[8];
    #pragma unroll
    for (int sub = 0; sub < 2; ++sub) {
      int kvb = kv0 + 16*sub;
      bf16x8 kf[2];
      #pragma unroll
      for (int ch = 0; ch < 2; ++ch)
        kf[ch] = *(const bf16x8*)&Kp[(size_t)(kvb + lo) * 64 + ch*32 + g*8];
      f32x4 st0 = zero4(), st1 = zero4();
      st0 = __builtin_amdgcn_mfma_f32_16x16x32_bf16(kf[0], qf0[0], st0, 0, 0, 0);
      st0 = __builtin_amdgcn_mfma_f32_16x16x32_bf16(kf[1], qf0[1], st0, 0, 0, 0);
      st1 = __builtin_amdgcn_mfma_f32_16x16x32_bf16(kf[0], qf1[0], st1, 0, 0, 0);
      st1 = __builtin_amdgcn_mfma_f32_16x16x32_bf16(kf[1], qf1[1], st1, 0, 0, 0);
      #pragma unroll
      for (int i = 0; i < 4; ++i) {
        int kvi = kvb + 4*g + i;
        s80[sub*4 + i] = (kvi <= q0 + lo)      ? st0[i] : -1e30f;
        s81[sub*4 + i] = (kvi <= q0 + 16 + lo) ? st1[i] : -1e30f;
      }
    }
    {
      float tmax = s80[0];
      #pragma unroll
      for (int j = 1; j < 8; ++j) tmax = fmaxf(tmax, s80[j]);
      tmax = fmaxf(tmax, __shfl_xor(tmax, 16));
      tmax = fmaxf(tmax, __shfl_xor(tmax, 32));
      if (!__all(tmax <= m0)) {
        float newm = fmaxf(m0, tmax);
        float resc = __expf(m0 - newm);
        ls0 *= resc; m0 = newm;
        #pragma unroll
        for (int i = 0; i < 4; ++i) {
          float rs = __shfl(resc, 4*g + i);
          of0[0][i] *= rs; of0[1][i] *= rs; of0[2][i] *= rs; of0[3][i] *= rs;
        }
      }
    }
    {
      float tmax = s81[0];
      #pragma unroll
      for (int j = 1; j < 8; ++j) tmax = fmaxf(tmax, s81[j]);
      tmax = fmaxf(tmax, __shfl_xor(tmax, 16));
      tmax = fmaxf(tmax, __shfl_xor(tmax, 32));
      if (!__all(tmax <= m1)) {
        float newm = fmaxf(m1, tmax);
        float resc = __expf(m1 - newm);
        ls1 *= resc; m1 = newm;
        #pragma unroll
        for (int i = 0; i < 4; ++i) {
          float rs = __shfl(resc, 4*g + i);
          of1[0][i] *= rs; of1[1][i] *= rs; of1[2][i] *= rs; of1[3][i] *= rs;
        }
      }
    }
    float p80[8], p81[8]; float ps0 = 0.f, ps1 = 0.f;
    #pragma unroll
    for (int j = 0; j < 8; ++j) {
      p80[j] = __expf(s80[j] - m0); ps0 += p80[j];
      p81[j] = __expf(s81[j] - m1); ps1 += p81[j];
    }
    ps0 += __shfl_xor(ps0, 16); ps0 += __shfl_xor(ps0, 32); ls0 += ps0;
    ps1 += __shfl_xor(ps1, 16); ps1 += __shfl_xor(ps1, 32); ls1 += ps1;
    unsigned int q40[4], q41[4];
    #pragma unroll
    for (int c = 0; c < 4; ++c) {
      asm("v_cvt_pk_bf16_f32 %0, %1, %2" : "=v"(q40[c]) : "v"(p80[2*c]), "v"(p80[2*c+1]));
      asm("v_cvt_pk_bf16_f32 %0, %1, %2" : "=v"(q41[c]) : "v"(p81[2*c]), "v"(p81[2*c+1]));
    }
    union U { unsigned int wv[4]; bf16x8 v; } pu0, pu1;
    #pragma unroll
    for (int j = 0; j < 4; ++j) {
      int srcLane = lo + lg2 + ((j >> 1) << 4);
      unsigned int lo_w0 = (unsigned int)__shfl((int)q40[j & 1], srcLane);
      unsigned int hi_w0 = (unsigned int)__shfl((int)q40[2 + (j & 1)], srcLane);
      pu0.wv[j] = ghi ? hi_w0 : lo_w0;
      unsigned int lo_w1 = (unsigned int)__shfl((int)q41[j & 1], srcLane);
      unsigned int hi_w1 = (unsigned int)__shfl((int)q41[2 + (j & 1)], srcLane);
      pu1.wv[j] = ghi ? hi_w1 : lo_w1;
    }
    #pragma unroll
    for (int ch = 0; ch < 4; ++ch) {
      of0[ch] = __builtin_amdgcn_mfma_f32_16x16x32_bf16(pu0.v, vf[ch], of0[ch], 0, 0, 0);
      of1[ch] = __builtin_amdgcn_mfma_f32_16x16x32_bf16(pu1.v, vf[ch], of1[ch], 0, 0, 0);
    }
  }

  #pragma unroll
  for (int i = 0; i < 4; ++i) {
    float li0 = 1.f / __shfl(ls0, 4*g + i);
    float li1 = 1.f / __shfl(ls1, 4*g + i);
    of0[0][i] *= li0; of0[1][i] *= li0; of0[2][i] *= li0; of0[3][i] *= li0;
    of1[0][i] *= li1; of1[1][i] *= li1; of1[2][i] *= li1; of1[3][i] *= li1;
  }
  ushort_t* yb = y + ((size_t)b*Tn + q0) * Cn + h*64;
  #pragma unroll
  for (int ch = 0; ch < 4; ++ch)
    #pragma unroll
    for (int i = 0; i < 4; ++i) {
      yb[(size_t)(4*g + i) * Cn + ch*16 + lo] = f2bf(of0[ch][i]);
      yb[(size_t)(16 + 4*g + i) * Cn + ch*16 + lo] = f2bf(of1[ch][i]);
    }
}

// ---------------- launch ----------------
extern "C" void kernel_launch(void* const* d_in, const int* in_sizes, int n_in,
                              void* d_out, int out_size, void* d_ws, size_t ws_size,
                              hipStream_t stream) {
  const int*   idx     = (const int*)d_in[0];
  const float* tok_emb = (const float*)d_in[1];
  const float* pos_emb = (const float*)d_in[2];
  const float* ln1_g   = (const float*)d_in[3];
  const float* ln1_b   = (const float*)d_in[4];
  const float* qkv_w   = (const float*)d_in[5];
  const float* qkv_b   = (const float*)d_in[6];
  const float* aproj_w = (const float*)d_in[7];
  const float* aproj_b = (const float*)d_in[8];
  const float* ln2_g   = (const float*)d_in[9];
  const float* ln2_b   = (const float*)d_in[10];
  const float* fc_w    = (const float*)d_in[11];
  const float* fc_b    = (const float*)d_in[12];
  const float* mproj_w = (const float*)d_in[13];
  const float* mproj_b = (const float*)d_in[14];
  const float* lnf_g   = (const float*)d_in[15];
  const float* lnf_b   = (const float*)d_in[16];
  const float* head_w  = (const float*)d_in[17];
  float* out = (float*)d_out;

  char* ws = (char*)d_ws;
  float*    x    = (float*)(ws);                         // 12,582,912 B
  ushort_t* hA   = (ushort_t*)(ws + 12582912);           //  6,291,456 B
  ushort_t* hB   = (ushort_t*)(ws + 18874368);           // 25,165,824 B
  ushort_t* qkvh = (ushort_t*)(ws + 44040192);           // 25,165,824 B (q,k,vT,vtmp)
  ushort_t* wT   = (ushort_t*)(ws + 69206016);           // 77,463,552 B (4-layer pack / head Npad 50432)

  const int M = Bn * Tn;  // 4096
  dim3 tb(32, 8);

  embed_kernel<<<M, 192, 0, stream>>>(idx, tok_emb, pos_emb, x);
  tcvtAll_kernel<<<27648, tb, 0, stream>>>(qkv_w, aproj_w, fc_w, mproj_w, wT);
  for (int l = 0; l < Ln; ++l) {
    ushort_t* wTl = wT + (size_t)l * PACK_SZ;
    ln_kernel<<<M/4, 256, 0, stream>>>(x, ln1_g + l*Cn, ln1_b + l*Cn, hA);
    gemm256_kernel<3><<<dim3(M/256, 2304/128), 512, 0, stream>>>(hA, wTl + OFF_QKV, qkv_b + (size_t)l*3*Cn, qkvh, M, 2304, 768);
    vtrans_kernel<<<dim3(Tn/64, Bn*Hn), 256, 0, stream>>>(qkvh + 3*QKV_ELEMS, qkvh + 2*QKV_ELEMS);
    attn_kernel<<<dim3(64, Bn*Hn), 64, 0, stream>>>(qkvh, hA);
    gemm_kernel<1,64><<<dim3(M/64, 768/128), 256, 0, stream>>>(hA, wTl + OFF_APROJ, aproj_b + (size_t)l*Cn, x, x, M, 768, 768);
    ln_kernel<<<M/4, 256, 0, stream>>>(x, ln2_g + l*Cn, ln2_b + l*Cn, hA);
    gemm256_kernel<2><<<dim3(M/256, 3072/128), 512, 0, stream>>>(hA, wTl + OFF_FC, fc_b + (size_t)l*4*Cn, hB, M, 3072, 768);
    gemm_kernel<1,64><<<dim3(M/64, 768/128), 256, 0, stream>>>(hB, wTl + OFF_MPROJ, mproj_b + (size_t)l*Cn, x, x, M, 768, 3072);
  }
  ln_kernel<<<M/4, 256, 0, stream>>>(x, lnf_g, lnf_b, hA);
  tcvt_kernel<<<dim3(50432/32, 768/32), tb, 0, stream>>>(head_w, wT, 768, Vn, 50432);
  gemm256_kernel<0><<<dim3(M/256, 50432/128), 512, 0, stream>>>(hA, wT, nullptr, out, M, Vn, 768);
}

// Round 20
// 1535.717 us; speedup vs baseline: 1.0021x; 1.0002x over previous
//
#include <hip/hip_runtime.h>
#include <cstdint>
#include <cstddef>

#define Tn 2048
#define Bn 2
#define Hn 12
#define Cn 768
#define Ln 4
#define Vn 50257

typedef unsigned short ushort_t;
typedef __attribute__((ext_vector_type(8))) __bf16 bf16x8;
typedef __attribute__((ext_vector_type(8))) unsigned short u16x8;
typedef __attribute__((ext_vector_type(4))) unsigned short u16x4;
typedef __attribute__((ext_vector_type(4))) float f32x4;

static constexpr size_t QKV_ELEMS = (size_t)Bn * Hn * Tn * 64;  // 3,145,728
static constexpr size_t OFF_QKV = 0;
static constexpr size_t OFF_APROJ = 1769472;
static constexpr size_t OFF_FC = 2359296;
static constexpr size_t OFF_MPROJ = 4718592;
static constexpr size_t PACK_SZ = 7077888;

__device__ inline unsigned short f2bf(float f) {
  unsigned int u = __float_as_uint(f);
  unsigned int r = (u + 0x7fffu + ((u >> 16) & 1u)) >> 16;
  return (unsigned short)r;
}

__device__ inline f32x4 zero4() { f32x4 z; z[0]=0.f; z[1]=0.f; z[2]=0.f; z[3]=0.f; return z; }

__device__ inline void gload_lds16(const ushort_t* g, ushort_t* l) {
  __builtin_amdgcn_global_load_lds(
      (const __attribute__((address_space(1))) void*)g,
      (__attribute__((address_space(3))) void*)l, 16, 0, 0);
}

// bijective XCD-chunked swizzle (m204)
__device__ inline int swz_lin() {
  int nbm = gridDim.x;
  int lin = blockIdx.y * nbm + blockIdx.x;
  int nwg = nbm * gridDim.y;
  int q = nwg >> 3, r = nwg & 7, x = lin & 7, p = lin >> 3;
  return (x < r ? x * (q + 1) : r * (q + 1) + (x - r) * q) + p;
}

// ---------------- embedding (float4) ----------------
__global__ __launch_bounds__(192) void embed_kernel(const int* __restrict__ idx,
    const float* __restrict__ tok, const float* __restrict__ pos, float* __restrict__ x) {
  int row = blockIdx.x;
  int t = row & (Tn - 1);
  int token = idx[row];
  const f32x4* tr = (const f32x4*)(tok + (size_t)token * Cn);
  const f32x4* pr = (const f32x4*)(pos + (size_t)t * Cn);
  f32x4* xr = (f32x4*)(x + (size_t)row * Cn);
  xr[threadIdx.x] = tr[threadIdx.x] + pr[threadIdx.x];
}

// ---------------- layernorm -> bf16 (wave per row, float4) ----------------
__global__ __launch_bounds__(256) void ln_kernel(const float* __restrict__ x,
    const float* __restrict__ gam, const float* __restrict__ bet, ushort_t* __restrict__ out) {
  const int wv = threadIdx.x >> 6, lane = threadIdx.x & 63;
  const int row = blockIdx.x * 4 + wv;
  const f32x4* xr = (const f32x4*)(x + (size_t)row * Cn);
  f32x4 v[3]; float s = 0.f, s2 = 0.f;
  #pragma unroll
  for (int e = 0; e < 3; ++e) {
    v[e] = xr[lane + e*64];
    #pragma unroll
    for (int j = 0; j < 4; ++j) { s += v[e][j]; s2 += v[e][j]*v[e][j]; }
  }
  #pragma unroll
  for (int off = 32; off >= 1; off >>= 1) { s += __shfl_xor(s, off); s2 += __shfl_xor(s2, off); }
  float mean = s * (1.f / Cn);
  float var  = s2 * (1.f / Cn) - mean * mean;
  float rstd = rsqrtf(var + 1e-5f);
  const f32x4* g4 = (const f32x4*)gam;
  const f32x4* b4 = (const f32x4*)bet;
  u16x4* o4 = (u16x4*)(out + (size_t)row * Cn);
  #pragma unroll
  for (int e = 0; e < 3; ++e) {
    f32x4 gv = g4[lane + e*64], bv = b4[lane + e*64];
    u16x4 o;
    #pragma unroll
    for (int j = 0; j < 4; ++j) o[j] = f2bf((v[e][j] - mean) * rstd * gv[j] + bv[j]);
    o4[lane + e*64] = o;
  }
}

// ---------------- transpose + f32->bf16 (head weight) ----------------
__global__ __launch_bounds__(256) void tcvt_kernel(const float* __restrict__ in,
    ushort_t* __restrict__ out, int K, int N, int Npad) {
  __shared__ float tile[32][33];
  int n0 = blockIdx.x * 32, k0 = blockIdx.y * 32;
  int tx = threadIdx.x, ty = threadIdx.y;
  #pragma unroll
  for (int r = 0; r < 4; ++r) {
    int k = k0 + ty + 8*r;
    int n = n0 + tx;
    tile[ty + 8*r][tx] = (n < N) ? in[(size_t)k * N + n] : 0.f;
  }
  __syncthreads();
  #pragma unroll
  for (int r = 0; r < 4; ++r) {
    int n = n0 + ty + 8*r;
    out[(size_t)n * K + k0 + tx] = f2bf(tile[tx][ty + 8*r]);
  }
}

// ---------------- ALL layers' weight transpose+convert (one launch) ----------------
__global__ __launch_bounds__(256) void tcvtAll_kernel(const float* __restrict__ qkvw,
    const float* __restrict__ aprojw, const float* __restrict__ fcw,
    const float* __restrict__ mprojw, ushort_t* __restrict__ wT) {
  __shared__ float tile[32][33];
  int bid = blockIdx.x;
  const int layer = bid / 6912;
  int local = bid - layer * 6912;
  const float* in; int K, N, tilesX; size_t ooff;
  if (local < 1728)      { in = qkvw   + (size_t)layer*1769472; K = 768;  N = 2304; tilesX = 72; ooff = OFF_QKV; }
  else if (local < 2304) { in = aprojw + (size_t)layer*589824;  K = 768;  N = 768;  tilesX = 24; ooff = OFF_APROJ; local -= 1728; }
  else if (local < 4608) { in = fcw    + (size_t)layer*2359296; K = 768;  N = 3072; tilesX = 96; ooff = OFF_FC;    local -= 2304; }
  else                   { in = mprojw + (size_t)layer*2359296; K = 3072; N = 768;  tilesX = 24; ooff = OFF_MPROJ; local -= 4608; }
  int n0 = (local % tilesX) * 32, k0 = (local / tilesX) * 32;
  int tx = threadIdx.x, ty = threadIdx.y;
  ushort_t* out = wT + (size_t)layer * PACK_SZ + ooff;
  #pragma unroll
  for (int r = 0; r < 4; ++r)
    tile[ty + 8*r][tx] = in[(size_t)(k0 + ty + 8*r) * N + n0 + tx];
  __syncthreads();
  #pragma unroll
  for (int r = 0; r < 4; ++r)
    out[(size_t)(n0 + ty + 8*r) * K + k0 + tx] = f2bf(tile[tx][ty + 8*r]);
}

// ---------------- bf16 64x64 tile transpose: [BH,T,64] -> [BH,64,T] ----------------
__global__ __launch_bounds__(256) void vtrans_kernel(const ushort_t* __restrict__ vin,
                                                     ushort_t* __restrict__ vout) {
  __shared__ ushort_t tile[64][65];
  int t0 = blockIdx.x * 64;
  size_t bh = blockIdx.y;
  const ushort_t* src = vin + (bh * Tn + t0) * 64;
  int row = threadIdx.x >> 2, c0 = (threadIdx.x & 3) * 16;
  u16x8 a = *(const u16x8*)&src[(size_t)row * 64 + c0];
  u16x8 b = *(const u16x8*)&src[(size_t)row * 64 + c0 + 8];
  #pragma unroll
  for (int j = 0; j < 8; ++j) { tile[row][c0 + j] = a[j]; tile[row][c0 + 8 + j] = b[j]; }
  __syncthreads();
  int d = threadIdx.x >> 2, tq = (threadIdx.x & 3) * 16;
  u16x8 o0, o1;
  #pragma unroll
  for (int j = 0; j < 8; ++j) { o0[j] = tile[tq + j][d]; o1[j] = tile[tq + 8 + j][d]; }
  ushort_t* dst = vout + (bh * 64 + d) * Tn + t0 + tq;
  *(u16x8*)&dst[0] = o0;
  *(u16x8*)&dst[8] = o1;
}

// ======== 256x128 8-wave GEMM: 3-buf ring (72KB -> 2 blocks/CU) + T2 swizzle, G=4 ========
// MODE 0: f32 = acc+bias ; 2: bf16 = gelu(acc+bias) ; 3: qkv scatter
template<int MODE>
__global__ __launch_bounds__(512) void gemm256_kernel(
    const ushort_t* __restrict__ A, const ushort_t* __restrict__ Bt,
    const float* __restrict__ bias, void* __restrict__ outp,
    int M, int N, int K) {
  constexpr int BUFE = 12288;
  __shared__ ushort_t lds[3 * BUFE];
  const int t = threadIdx.x;
  const int w = t >> 6, l = t & 63, lo = l & 15, g = l >> 4;
  const int wm = w >> 1, wn = w & 1;

  int bm, bn;
  {
    int seq = swz_lin();
    int gsz = 4 * gridDim.y;
    int grp = seq / gsz;
    int t2 = seq - grp * gsz;
    bn = t2 >> 2;
    bm = grp * 4 + (t2 & 3);
  }

  const ushort_t* gAb = A  + (size_t)bm * 256 * K;
  const ushort_t* gBb = Bt + (size_t)bn * 128 * K;

  f32x4 acc[4][4];
  #pragma unroll
  for (int i = 0; i < 4; ++i)
    #pragma unroll
    for (int j = 0; j < 4; ++j) acc[i][j] = zero4();

  auto stage = [&](int kt, int buf) {
    const int k0 = kt << 5;
    #pragma unroll
    for (int j = 0; j < 2; ++j) {
      const int q = j * 512 + t;
      const int r = q >> 2;
      const int cc = ((q & 3) ^ ((r >> 1) & 3)) << 3;
      gload_lds16(gAb + (size_t)r * K + k0 + cc,
                  &lds[buf * BUFE + (j * 512 + (w << 6)) * 8]);
    }
    {
      const int q = t;
      const int r = q >> 2;
      const int cc = ((q & 3) ^ ((r >> 1) & 3)) << 3;
      gload_lds16(gBb + (size_t)r * K + k0 + cc,
                  &lds[buf * BUFE + 8192 + (w << 6) * 8]);
    }
  };
  const int csw = ((lo >> 1) & 3) << 3;
  auto compute = [&](int buf) {
    const ushort_t* as = &lds[buf * BUFE];
    const ushort_t* bs = &lds[buf * BUFE + 8192];
    bf16x8 af[4], bfr[4];
    #pragma unroll
    for (int mi = 0; mi < 4; ++mi)
      af[mi] = *(const bf16x8*)&as[(wm*64 + mi*16 + lo) * 32 + ((g*8) ^ csw)];
    #pragma unroll
    for (int ni = 0; ni < 4; ++ni)
      bfr[ni] = *(const bf16x8*)&bs[(wn*64 + ni*16 + lo) * 32 + ((g*8) ^ csw)];
    __builtin_amdgcn_s_setprio(1);
    #pragma unroll
    for (int mi = 0; mi < 4; ++mi)
      #pragma unroll
      for (int ni = 0; ni < 4; ++ni)
        acc[mi][ni] = __builtin_amdgcn_mfma_f32_16x16x32_bf16(af[mi], bfr[ni], acc[mi][ni], 0, 0, 0);
    __builtin_amdgcn_s_setprio(0);
  };

  const int NK = K >> 5;
  stage(0, 0); stage(1, 1); stage(2, 2);
  asm volatile("s_waitcnt vmcnt(6)" ::: "memory");
  __builtin_amdgcn_s_barrier();

  int buf = 0;
  #pragma unroll 1
  for (int kt = 0; kt < NK; ++kt) {
    compute(buf);
    asm volatile("s_waitcnt lgkmcnt(0)" ::: "memory");
    __builtin_amdgcn_s_barrier();
    if (kt + 3 < NK) {
      stage(kt + 3, buf);
      asm volatile("s_waitcnt vmcnt(6)" ::: "memory");
    } else if (kt + 2 < NK) {
      asm volatile("s_waitcnt vmcnt(3)" ::: "memory");
    } else {
      asm volatile("s_waitcnt vmcnt(0)" ::: "memory");
    }
    __builtin_amdgcn_s_barrier();
    buf = (buf == 2) ? 0 : buf + 1;
  }

  #pragma unroll
  for (int mi = 0; mi < 4; ++mi) {
    #pragma unroll
    for (int ni = 0; ni < 4; ++ni) {
      int colg = bn*128 + wn*64 + ni*16 + lo;
      if (colg < N) {
        float bv = bias ? bias[colg] : 0.f;
        #pragma unroll
        for (int i = 0; i < 4; ++i) {
          int rowg = bm*256 + wm*64 + mi*16 + 4*g + i;
          float vv = acc[mi][ni][i] + bv;
          if (MODE == 0) {
            ((float*)outp)[(size_t)rowg * N + colg] = vv;
          } else if (MODE == 2) {
            float ge = 0.5f * vv * (1.f + erff(vv * 0.70710678118f));
            ((ushort_t*)outp)[(size_t)rowg * N + colg] = f2bf(ge);
          } else {
            int which = colg / Cn;
            int rem = colg - which * Cn;
            int h = rem >> 6, d = rem & 63;
            int b = rowg >> 11, tt = rowg & (Tn - 1);
            ushort_t* qb = (ushort_t*)outp;
            size_t bh = (size_t)(b * Hn + h);
            size_t off = (bh * Tn + tt) * 64 + d;
            if (which == 0)      qb[off] = f2bf(vv * 0.125f);
            else if (which == 1) qb[QKV_ELEMS + off] = f2bf(vv);
            else                 qb[3*QKV_ELEMS + off] = f2bf(vv);   // staging; vtrans -> 2*QKV
          }
        }
      }
    }
  }
}

// ======== layer GEMM (aproj/mproj): 3-buf ring + T2 swizzle (64 tile, 4 waves), G=4 ========
template<int MODE, int TM>
__global__ __launch_bounds__(256) void gemm_kernel(
    const ushort_t* __restrict__ A, const ushort_t* __restrict__ Bt,
    const float* __restrict__ bias, void* __restrict__ outp,
    const float* __restrict__ res, int M, int N, int K) {
  constexpr int MI = TM / 32;
  constexpr int ASZ = TM * 32;
  constexpr int BUFE = ASZ + 4096;
  constexpr int LPT = TM/64 + 2;
  __shared__ ushort_t lds[3 * BUFE];
  const int t = threadIdx.x;
  int bm, bn;
  {
    int seq = swz_lin();
    const int G = 4;
    int gsz = G * gridDim.y;
    int grp = seq / gsz;
    int t2 = seq - grp * gsz;
    bn = t2 / G;
    bm = grp * G + (t2 - bn * G);
  }
  const int w = t >> 6, l = t & 63, lo = l & 15, g = l >> 4;
  const int wm = w >> 1, wn = w & 1;

  f32x4 acc[MI][4];
  #pragma unroll
  for (int i = 0; i < MI; ++i)
    #pragma unroll
    for (int j = 0; j < 4; ++j) acc[i][j] = zero4();

  const ushort_t* gAb = A  + (size_t)bm * TM * K;
  const ushort_t* gBb = Bt + (size_t)bn * 128 * K;

  auto stage = [&](int kt, int buf) {
    const int k0 = kt << 5;
    #pragma unroll
    for (int j = 0; j < TM/64; ++j) {
      const int q = j * 256 + t;
      const int r = q >> 2;
      const int cc = ((q & 3) ^ ((r >> 1) & 3)) << 3;
      gload_lds16(gAb + (size_t)r * K + k0 + cc, &lds[buf*BUFE + (j*256 + w*64)*8]);
    }
    #pragma unroll
    for (int j = 0; j < 2; ++j) {
      const int q = j * 256 + t;
      const int r = q >> 2;
      const int cc = ((q & 3) ^ ((r >> 1) & 3)) << 3;
      gload_lds16(gBb + (size_t)r * K + k0 + cc, &lds[buf*BUFE + ASZ + (j*256 + w*64)*8]);
    }
  };
  const int csw = ((lo >> 1) & 3) << 3;
  auto compute = [&](int buf) {
    const ushort_t* as = &lds[buf * BUFE];
    const ushort_t* bs = &lds[buf * BUFE + ASZ];
    bf16x8 af[MI], bfr[4];
    #pragma unroll
    for (int mi = 0; mi < MI; ++mi)
      af[mi] = *(const bf16x8*)&as[(wm*(TM/2) + mi*16 + lo) * 32 + ((g*8) ^ csw)];
    #pragma unroll
    for (int ni = 0; ni < 4; ++ni)
      bfr[ni] = *(const bf16x8*)&bs[(wn*64 + ni*16 + lo) * 32 + ((g*8) ^ csw)];
    __builtin_amdgcn_s_setprio(1);
    #pragma unroll
    for (int mi = 0; mi < MI; ++mi)
      #pragma unroll
      for (int ni = 0; ni < 4; ++ni)
        acc[mi][ni] = __builtin_amdgcn_mfma_f32_16x16x32_bf16(af[mi], bfr[ni], acc[mi][ni], 0, 0, 0);
    __builtin_amdgcn_s_setprio(0);
  };

  const int NK = K >> 5;
  stage(0, 0); stage(1, 1); stage(2, 2);
  if constexpr (LPT == 4) asm volatile("s_waitcnt vmcnt(8)" ::: "memory");
  else                    asm volatile("s_waitcnt vmcnt(6)" ::: "memory");
  __builtin_amdgcn_s_barrier();

  int buf = 0;
  #pragma unroll 1
  for (int kt = 0; kt < NK; ++kt) {
    compute(buf);
    asm volatile("s_waitcnt lgkmcnt(0)" ::: "memory");
    __builtin_amdgcn_s_barrier();
    if (kt + 3 < NK) {
      stage(kt + 3, buf);
      if constexpr (LPT == 4) asm volatile("s_waitcnt vmcnt(8)" ::: "memory");
      else                    asm volatile("s_waitcnt vmcnt(6)" ::: "memory");
    } else if (kt + 2 < NK) {
      if constexpr (LPT == 4) asm volatile("s_waitcnt vmcnt(4)" ::: "memory");
      else                    asm volatile("s_waitcnt vmcnt(3)" ::: "memory");
    } else {
      asm volatile("s_waitcnt vmcnt(0)" ::: "memory");
    }
    __builtin_amdgcn_s_barrier();
    buf = (buf == 2) ? 0 : buf + 1;
  }

  #pragma unroll
  for (int mi = 0; mi < MI; ++mi) {
    #pragma unroll
    for (int ni = 0; ni < 4; ++ni) {
      int colg = bn*128 + wn*64 + ni*16 + lo;
      if (colg < N) {
        float bv = bias ? bias[colg] : 0.f;
        #pragma unroll
        for (int i = 0; i < 4; ++i) {
          int rowg = bm*TM + wm*(TM/2) + mi*16 + 4*g + i;
          size_t off = (size_t)rowg * N + colg;
          float vv = acc[mi][ni][i] + bv;
          ((float*)outp)[off] = res[off] + vv;
        }
      }
    }
  }
}

// ---------------- flash attention (causal), 1 wave / 32 q-rows (2 halves share K/V) ----------------
__global__ __launch_bounds__(64) void attn_kernel(const ushort_t* __restrict__ qkvh,
                                                  ushort_t* __restrict__ y) {
  const int l = threadIdx.x;
  const int lo = l & 15, g = l >> 4;
  int nl = swz_lin();
  const int qt = 63 - (nl & 63);
  const int bh = nl >> 6;
  const int b = bh / Hn, h = bh % Hn;
  const int q0 = qt * 32;
  const ushort_t* Qp = qkvh + (size_t)bh * Tn * 64;
  const ushort_t* Kp = qkvh + QKV_ELEMS + (size_t)bh * Tn * 64;
  const ushort_t* Vt = qkvh + 2*QKV_ELEMS + (size_t)bh * 64 * Tn;

  bf16x8 qf0[2], qf1[2];
  #pragma unroll
  for (int ch = 0; ch < 2; ++ch) {
    qf0[ch] = *(const bf16x8*)&Qp[(size_t)(q0 + lo) * 64 + ch*32 + g*8];
    qf1[ch] = *(const bf16x8*)&Qp[(size_t)(q0 + 16 + lo) * 64 + ch*32 + g*8];
  }

  f32x4 of0[4], of1[4];
  #pragma unroll
  for (int ch = 0; ch < 4; ++ch) { of0[ch] = zero4(); of1[ch] = zero4(); }
  float m0 = -1e30f, m1 = -1e30f, ls0 = 0.f, ls1 = 0.f;
  const int nkv = q0 + 32;
  const bool ghi = (g >= 2);
  const int lg2 = (g & 1) * 32;

  for (int kv0 = 0; kv0 < nkv; kv0 += 32) {
    bf16x8 vf[4];
    #pragma unroll
    for (int ch = 0; ch < 4; ++ch)
      vf[ch] = *(const bf16x8*)&Vt[(size_t)(ch*16 + lo) * Tn + kv0 + g*8];

    float s80[8], s81[8];
    #pragma unroll
    for (int sub = 0; sub < 2; ++sub) {
      int kvb = kv0 + 16*sub;
      bf16x8 kf[2];
      #pragma unroll
      for (int ch = 0; ch < 2; ++ch)
        kf[ch] = *(const bf16x8*)&Kp[(size_t)(kvb + lo) * 64 + ch*32 + g*8];
      f32x4 st0 = zero4(), st1 = zero4();
      st0 = __builtin_amdgcn_mfma_f32_16x16x32_bf16(kf[0], qf0[0], st0, 0, 0, 0);
      st0 = __builtin_amdgcn_mfma_f32_16x16x32_bf16(kf[1], qf0[1], st0, 0, 0, 0);
      st1 = __builtin_amdgcn_mfma_f32_16x16x32_bf16(kf[0], qf1[0], st1, 0, 0, 0);
      st1 = __builtin_amdgcn_mfma_f32_16x16x32_bf16(kf[1], qf1[1], st1, 0, 0, 0);
      #pragma unroll
      for (int i = 0; i < 4; ++i) {
        int kvi = kvb + 4*g + i;
        s80[sub*4 + i] = (kvi <= q0 + lo)      ? st0[i] : -1e30f;
        s81[sub*4 + i] = (kvi <= q0 + 16 + lo) ? st1[i] : -1e30f;
      }
    }
    {
      float tmax = s80[0];
      #pragma unroll
      for (int j = 1; j < 8; ++j) tmax = fmaxf(tmax, s80[j]);
      tmax = fmaxf(tmax, __shfl_xor(tmax, 16));
      tmax = fmaxf(tmax, __shfl_xor(tmax, 32));
      if (!__all(tmax <= m0)) {
        float newm = fmaxf(m0, tmax);
        float resc = __expf(m0 - newm);
        ls0 *= resc; m0 = newm;
        #pragma unroll
        for (int i = 0; i < 4; ++i) {
          float rs = __shfl(resc, 4*g + i);
          of0[0][i] *= rs; of0[1][i] *= rs; of0[2][i] *= rs; of0[3][i] *= rs;
        }
      }
    }
    {
      float tmax = s81[0];
      #pragma unroll
      for (int j = 1; j < 8; ++j) tmax = fmaxf(tmax, s81[j]);
      tmax = fmaxf(tmax, __shfl_xor(tmax, 16));
      tmax = fmaxf(tmax, __shfl_xor(tmax, 32));
      if (!__all(tmax <= m1)) {
        float newm = fmaxf(m1, tmax);
        float resc = __expf(m1 - newm);
        ls1 *= resc; m1 = newm;
        #pragma unroll
        for (int i = 0; i < 4; ++i) {
          float rs = __shfl(resc, 4*g + i);
          of1[0][i] *= rs; of1[1][i] *= rs; of1[2][i] *= rs; of1[3][i] *= rs;
        }
      }
    }
    float p80[8], p81[8]; float ps0 = 0.f, ps1 = 0.f;
    #pragma unroll
    for (int j = 0; j < 8; ++j) {
      p80[j] = __expf(s80[j] - m0); ps0 += p80[j];
      p81[j] = __expf(s81[j] - m1); ps1 += p81[j];
    }
    ps0 += __shfl_xor(ps0, 16); ps0 += __shfl_xor(ps0, 32); ls0 += ps0;
    ps1 += __shfl_xor(ps1, 16); ps1 += __shfl_xor(ps1, 32); ls1 += ps1;
    unsigned int q40[4], q41[4];
    #pragma unroll
    for (int c = 0; c < 4; ++c) {
      asm("v_cvt_pk_bf16_f32 %0, %1, %2" : "=v"(q40[c]) : "v"(p80[2*c]), "v"(p80[2*c+1]));
      asm("v_cvt_pk_bf16_f32 %0, %1, %2" : "=v"(q41[c]) : "v"(p81[2*c]), "v"(p81[2*c+1]));
    }
    union U { unsigned int wv[4]; bf16x8 v; } pu0, pu1;
    #pragma unroll
    for (int j = 0; j < 4; ++j) {
      int srcLane = lo + lg2 + ((j >> 1) << 4);
      unsigned int lo_w0 = (unsigned int)__shfl((int)q40[j & 1], srcLane);
      unsigned int hi_w0 = (unsigned int)__shfl((int)q40[2 + (j & 1)], srcLane);
      pu0.wv[j] = ghi ? hi_w0 : lo_w0;
      unsigned int lo_w1 = (unsigned int)__shfl((int)q41[j & 1], srcLane);
      unsigned int hi_w1 = (unsigned int)__shfl((int)q41[2 + (j & 1)], srcLane);
      pu1.wv[j] = ghi ? hi_w1 : lo_w1;
    }
    #pragma unroll
    for (int ch = 0; ch < 4; ++ch) {
      of0[ch] = __builtin_amdgcn_mfma_f32_16x16x32_bf16(pu0.v, vf[ch], of0[ch], 0, 0, 0);
      of1[ch] = __builtin_amdgcn_mfma_f32_16x16x32_bf16(pu1.v, vf[ch], of1[ch], 0, 0, 0);
    }
  }

  #pragma unroll
  for (int i = 0; i < 4; ++i) {
    float li0 = 1.f / __shfl(ls0, 4*g + i);
    float li1 = 1.f / __shfl(ls1, 4*g + i);
    of0[0][i] *= li0; of0[1][i] *= li0; of0[2][i] *= li0; of0[3][i] *= li0;
    of1[0][i] *= li1; of1[1][i] *= li1; of1[2][i] *= li1; of1[3][i] *= li1;
  }
  ushort_t* yb = y + ((size_t)b*Tn + q0) * Cn + h*64;
  #pragma unroll
  for (int ch = 0; ch < 4; ++ch)
    #pragma unroll
    for (int i = 0; i < 4; ++i) {
      yb[(size_t)(4*g + i) * Cn + ch*16 + lo] = f2bf(of0[ch][i]);
      yb[(size_t)(16 + 4*g + i) * Cn + ch*16 + lo] = f2bf(of1[ch][i]);
    }
}

// ---------------- launch ----------------
extern "C" void kernel_launch(void* const* d_in, const int* in_sizes, int n_in,
                              void* d_out, int out_size, void* d_ws, size_t ws_size,
                              hipStream_t stream) {
  const int*   idx     = (const int*)d_in[0];
  const float* tok_emb = (const float*)d_in[1];
  const float* pos_emb = (const float*)d_in[2];
  const float* ln1_g   = (const float*)d_in[3];
  const float* ln1_b   = (const float*)d_in[4];
  const float* qkv_w   = (const float*)d_in[5];
  const float* qkv_b   = (const float*)d_in[6];
  const float* aproj_w = (const float*)d_in[7];
  const float* aproj_b = (const float*)d_in[8];
  const float* ln2_g   = (const float*)d_in[9];
  const float* ln2_b   = (const float*)d_in[10];
  const float* fc_w    = (const float*)d_in[11];
  const float* fc_b    = (const float*)d_in[12];
  const float* mproj_w = (const float*)d_in[13];
  const float* mproj_b = (const float*)d_in[14];
  const float* lnf_g   = (const float*)d_in[15];
  const float* lnf_b   = (const float*)d_in[16];
  const float* head_w  = (const float*)d_in[17];
  float* out = (float*)d_out;

  char* ws = (char*)d_ws;
  float*    x    = (float*)(ws);                         // 12,582,912 B
  ushort_t* hA   = (ushort_t*)(ws + 12582912);           //  6,291,456 B
  ushort_t* hB   = (ushort_t*)(ws + 18874368);           // 25,165,824 B
  ushort_t* qkvh = (ushort_t*)(ws + 44040192);           // 25,165,824 B (q,k,vT,vtmp)
  ushort_t* wT   = (ushort_t*)(ws + 69206016);           // 77,463,552 B (4-layer pack / head Npad 50432)

  const int M = Bn * Tn;  // 4096
  dim3 tb(32, 8);

  embed_kernel<<<M, 192, 0, stream>>>(idx, tok_emb, pos_emb, x);
  tcvtAll_kernel<<<27648, tb, 0, stream>>>(qkv_w, aproj_w, fc_w, mproj_w, wT);
  for (int l = 0; l < Ln; ++l) {
    ushort_t* wTl = wT + (size_t)l * PACK_SZ;
    ln_kernel<<<M/4, 256, 0, stream>>>(x, ln1_g + l*Cn, ln1_b + l*Cn, hA);
    gemm256_kernel<3><<<dim3(M/256, 2304/128), 512, 0, stream>>>(hA, wTl + OFF_QKV, qkv_b + (size_t)l*3*Cn, qkvh, M, 2304, 768);
    vtrans_kernel<<<dim3(Tn/64, Bn*Hn), 256, 0, stream>>>(qkvh + 3*QKV_ELEMS, qkvh + 2*QKV_ELEMS);
    attn_kernel<<<dim3(64, Bn*Hn), 64, 0, stream>>>(qkvh, hA);
    gemm_kernel<1,64><<<dim3(M/64, 768/128), 256, 0, stream>>>(hA, wTl + OFF_APROJ, aproj_b + (size_t)l*Cn, x, x, M, 768, 768);
    ln_kernel<<<M/4, 256, 0, stream>>>(x, ln2_g + l*Cn, ln2_b + l*Cn, hA);
    gemm256_kernel<2><<<dim3(M/256, 3072/128), 512, 0, stream>>>(hA, wTl + OFF_FC, fc_b + (size_t)l*4*Cn, hB, M, 3072, 768);
    gemm_kernel<1,64><<<dim3(M/64, 768/128), 256, 0, stream>>>(hB, wTl + OFF_MPROJ, mproj_b + (size_t)l*Cn, x, x, M, 768, 3072);
  }
  ln_kernel<<<M/4, 256, 0, stream>>>(x, lnf_g, lnf_b, hA);
  tcvt_kernel<<<dim3(50432/32, 768/32), tb, 0, stream>>>(head_w, wT, 768, Vn, 50432);
  gemm256_kernel<0><<<dim3(M/256, 50432/128), 512, 0, stream>>>(hA, wT, nullptr, out, M, Vn, 768);
}